// Round 18
// baseline (61.728 us; speedup 1.0000x reference)
//
#include <hip/hip_runtime.h>
#include <math.h>
#include <stdint.h>

// Router: scores = x @ emb^T [32768 x 64] fp32-accurate, top-2 + 2-way softmax.
//
// Error-free split-bf16 MFMA (rounds 9-17, passes): 3 bf16 limbs per fp32
// operand, 6 limb-product MFMA passes accumulated in fp32 (~3e-7 error).
// Round-17 null isolated to REGISTER STARVATION: __launch_bounds__(512,8)
// squeezed VGPR to 28 (the same body compiles to 52 at (512,4)), so doubling
// occupancy (38->67%) bought nothing -- each wave serialized ds_read->use.
// 52 VGPR <= 64 = the HW threshold for 8 waves/SIMD, so (512,4) keeps the
// SAME 4-blocks/CU, 8-waves/SIMD occupancy (LDS-limited at 40960 B) while
// giving waves working registers. Single-variable change vs round 17.

typedef __attribute__((ext_vector_type(8))) short short8;
typedef __attribute__((ext_vector_type(4))) float f32x4;

constexpr int HDIM = 1024;
constexpr int NEXP = 64;
constexpr int TPB  = 32;            // tokens per block
constexpr int NTHREADS = 512;       // 8 waves
constexpr int NCHUNK = 16;          // 64-k chunks

__device__ __forceinline__ uint32_t cvtpk_bf16(float lo, float hi) {
    uint32_t r;
    asm("v_cvt_pk_bf16_f32 %0, %1, %2" : "=v"(r) : "v"(lo), "v"(hi));
    return r;
}

// RNE 3-limb bf16 split of 8 fp32 values; outputs packed frag words.
__device__ __forceinline__ void split8(const float4& A, const float4& B,
                                       uint32_t w0[4], uint32_t w1[4],
                                       uint32_t w2[4])
{
    const float p[8] = {A.x, A.y, A.z, A.w, B.x, B.y, B.z, B.w};
#pragma unroll
    for (int m = 0; m < 4; ++m) {
        const float lo = p[2 * m], hi = p[2 * m + 1];
        const uint32_t c0 = cvtpk_bf16(lo, hi);
        const float l0 = __uint_as_float(c0 << 16);
        const float h0 = __uint_as_float(c0 & 0xFFFF0000u);
        const float rl = lo - l0, rh = hi - h0;         // exact
        const uint32_t c1 = cvtpk_bf16(rl, rh);
        const float l1 = __uint_as_float(c1 << 16);
        const float h1 = __uint_as_float(c1 & 0xFFFF0000u);
        const uint32_t c2 = cvtpk_bf16(rl - l1, rh - h1);
        w0[m] = c0; w1[m] = c1; w2[m] = c2;
    }
}

__device__ __forceinline__ short8 frag_of(uint32_t a, uint32_t b,
                                          uint32_t c, uint32_t d) {
    union { uint4 u; short8 s; } cv;
    cv.u = make_uint4(a, b, c, d);
    return cv.s;
}
__device__ __forceinline__ short8 frag_of4(const uint4& v) {
    union { uint4 u; short8 s; } cv;
    cv.u = v;
    return cv.s;
}

// prepack, chunk-contiguous for linear staging (same layout as rounds 15-17):
// wsb[c*1536 + ((jkk*4 + t)*3 + limb)*64 + lane] =
//   limb of emb[t*16+(lane&15)][(c*2+jkk)*32 + (lane>>4)*8 .. +7] as bf16x8.
__global__ __launch_bounds__(256)
void prepack_kernel(const float* __restrict__ emb, uint4* __restrict__ wsb)
{
    const int f2   = blockIdx.x * 256 + threadIdx.x;   // 0..8191
    const int lane = f2 & 63;
    const int t    = (f2 >> 6) & 3;
    const int jkk  = (f2 >> 8) & 1;
    const int c    = f2 >> 9;
    const int e    = t * 16 + (lane & 15);
    const int k0   = (c * 2 + jkk) * 32 + (lane >> 4) * 8;
    const float4 A = *(const float4*)(emb + (size_t)e * HDIM + k0);
    const float4 B = *(const float4*)(emb + (size_t)e * HDIM + k0 + 4);
    uint32_t w0[4], w1[4], w2[4];
    split8(A, B, w0, w1, w2);
    const int ob = c * 1536 + ((jkk * 4 + t) * 3) * 64 + lane;
    wsb[ob]       = make_uint4(w0[0], w0[1], w0[2], w0[3]);
    wsb[ob + 64]  = make_uint4(w1[0], w1[1], w1[2], w1[3]);
    wsb[ob + 128] = make_uint4(w2[0], w2[1], w2[2], w2[3]);
}

__global__ __launch_bounds__(NTHREADS, 4)
void router_kernel(const float* __restrict__ x,
                   const uint4* __restrict__ wsb,
                   float* __restrict__ out)
{
    // EXACTLY 40960 B -> 4 blocks/CU (LDS-limited). Epilogue aliases into xs.
    __shared__ float4 xs[2][TPB][16];   // 16 KiB, x[token][quad^(token&15)]
    __shared__ uint4  bs[1536];         // 24 KiB, staged B-frags (one chunk)

    const int tid  = threadIdx.x;
    const int lane = tid & 63;
    const int W    = tid >> 6;          // wave 0..7
    const int m    = W >> 2;            // token half: rows 16m..16m+15
    const int t    = W & 3;             // expert tile: experts [16t, 16t+16)
    const int tok0 = blockIdx.x * TPB;
    const int col  = lane & 15;
    const int grp  = lane >> 4;

    // x stage: 1 load/thread (512 threads cover 32 rows x 16 quads);
    // XOR swizzle folded into the per-lane GLOBAL source; LDS dest linear.
#define STAGE_X(P, C)                                                          \
    do {                                                                       \
        const int r_ = tid >> 4, q_ = tid & 15;                                \
        const float* src = x + (size_t)(tok0 + r_) * HDIM + (C) * 64           \
                             + ((q_ ^ (r_ & 15)) * 4);                         \
        __builtin_amdgcn_global_load_lds(                                      \
            (const __attribute__((address_space(1))) void*)src,                \
            (__attribute__((address_space(3))) void*)&xs[P][r_][q_],           \
            16, 0, 0);                                                         \
    } while (0)

    // B stage: 3 loads/thread, chunk-contiguous wsb image -> bs (linear).
#define STAGE_B(C)                                                             \
    do {                                                                       \
        _Pragma("unroll")                                                      \
        for (int jj = 0; jj < 3; ++jj) {                                       \
            const int f_ = jj * NTHREADS + tid;                                \
            __builtin_amdgcn_global_load_lds(                                  \
                (const __attribute__((address_space(1))) void*)                \
                    (wsb + (C) * 1536 + f_),                                   \
                (__attribute__((address_space(3))) void*)&bs[f_],              \
                16, 0, 0);                                                     \
        }                                                                      \
    } while (0)

    f32x4 acc = {0, 0, 0, 0};           // 16 tokens x 16 experts

    STAGE_X(0, 0);
    STAGE_B(0);
    STAGE_X(1, 1);

#pragma unroll 1
    for (int c = 0; c < NCHUNK; ++c) {
        // outstanding at top: B(c)[3] + x(c+1)[1] (c<15) -> vmcnt(1) retires
        // B(c) (and the older x(c)), keeps x(c+1) in flight. Last iter: 0.
        if (c < NCHUNK - 1) {
            asm volatile("s_waitcnt vmcnt(1)" ::: "memory");
        } else {
            asm volatile("s_waitcnt vmcnt(0)" ::: "memory");
        }
        __builtin_amdgcn_s_barrier();
        asm volatile("" ::: "memory");

        const int p = c & 1;
#pragma unroll
        for (int jkk = 0; jkk < 2; ++jkk) {
            const int q0 = jkk * 8 + grp * 2;
            const int r  = 16 * m + col;
            const float4 a0 = xs[p][r][(q0    ) ^ col];
            const float4 a1 = xs[p][r][(q0 + 1) ^ col];

            uint32_t wa0[4], wa1[4], wa2[4];
            split8(a0, a1, wa0, wa1, wa2);
            const short8 fA0 = frag_of(wa0[0], wa0[1], wa0[2], wa0[3]);
            const short8 fA1 = frag_of(wa1[0], wa1[1], wa1[2], wa1[3]);
            const short8 fA2 = frag_of(wa2[0], wa2[1], wa2[2], wa2[3]);

            const int bf = ((jkk * 4 + t) * 3) * 64 + lane;
            const short8 fb0 = frag_of4(bs[bf]);
            const short8 fb1 = frag_of4(bs[bf + 64]);
            const short8 fb2 = frag_of4(bs[bf + 128]);

            acc = __builtin_amdgcn_mfma_f32_16x16x32_bf16(fA2, fb0, acc, 0,0,0);
            acc = __builtin_amdgcn_mfma_f32_16x16x32_bf16(fA0, fb2, acc, 0,0,0);
            acc = __builtin_amdgcn_mfma_f32_16x16x32_bf16(fA1, fb1, acc, 0,0,0);
            acc = __builtin_amdgcn_mfma_f32_16x16x32_bf16(fA1, fb0, acc, 0,0,0);
            acc = __builtin_amdgcn_mfma_f32_16x16x32_bf16(fA0, fb1, acc, 0,0,0);
            acc = __builtin_amdgcn_mfma_f32_16x16x32_bf16(fA0, fb0, acc, 0,0,0);
        }

        __builtin_amdgcn_s_barrier();   // all waves done reading bs / xs[p]
        asm volatile("" ::: "memory");
        if (c + 1 < NCHUNK) STAGE_B(c + 1);
        if (c + 2 < NCHUNK) STAGE_X(p, c + 2);   // xs[p] just fully consumed
    }
#undef STAGE_X
#undef STAGE_B

    // ---- epilogue: alias candidate buffers into xs (loop done) ----
    __syncthreads();
    float4* cand  = &xs[0][0][0];       // [4 tiles][32 tokens]
    float4* cand2 = &xs[1][0][0];       // [32 tokens] (p1,p2,E1,E2)

#define INS(v, e)                                                              \
    do {                                                                       \
        const float _v = (v); const int _e = (e);                              \
        if (_v > V1 || (_v == V1 && _e < E1)) {                                \
            V2 = V1; E2 = E1; V1 = _v; E1 = _e;                                \
        } else if (_v > V2 || (_v == V2 && _e < E2)) {                         \
            V2 = _v; E2 = _e;                                                  \
        }                                                                      \
    } while (0)

#pragma unroll
    for (int i = 0; i < 4; ++i) {
        // acc[i]: token 16m + grp*4 + i, expert 16t + col
        float V1 = acc[i]; int E1 = 16 * t + col;
        float V2 = -INFINITY; int E2 = NEXP;
#pragma unroll
        for (int mk = 1; mk <= 8; mk <<= 1) {
            const float pv1 = __shfl_xor(V1, mk, 64);
            const int   pe1 = __shfl_xor(E1, mk, 64);
            const float pv2 = __shfl_xor(V2, mk, 64);
            const int   pe2 = __shfl_xor(E2, mk, 64);
            INS(pv1, pe1);
            INS(pv2, pe2);
        }
        if (col == 0) {
            float4 cd;
            cd.x = V1; cd.y = __int_as_float(E1);
            cd.z = V2; cd.w = __int_as_float(E2);
            cand[t * TPB + 16 * m + grp * 4 + i] = cd;
        }
    }
    __syncthreads();

    // ---- merge 4 expert tiles per token (ascending tile => lowest-idx ties)
    if (tid < TPB) {
        float V1 = -INFINITY, V2 = -INFINITY; int E1 = 0, E2 = 0;
#pragma unroll
        for (int tt = 0; tt < 4; ++tt) {
            const float4 q = cand[tt * TPB + tid];
            const float a = q.x; const int ea = __float_as_int(q.y);
            const float b = q.z; const int eb = __float_as_int(q.w);
            if (a > V1)      { V2 = V1; E2 = E1; V1 = a; E1 = ea; }
            else if (a > V2) { V2 = a; E2 = ea; }
            if (b > V1)      { V2 = V1; E2 = E1; V1 = b; E1 = eb; }
            else if (b > V2) { V2 = b; E2 = eb; }
        }
        const float et = expf(V2 - V1);
        float4 c2;
        c2.x = 1.f / (1.f + et);
        c2.y = et / (1.f + et);
        c2.z = __int_as_float(E1);
        c2.w = __int_as_float(E2);
        cand2[tid] = c2;
    }
#undef INS
    __syncthreads();

    // ---- coalesced output: 32 tokens x 16 quads = 512 float4 (1/thread) ----
    {
        const int tt = tid >> 4, q = tid & 15;
        const float4 c = cand2[tt];
        const int E1 = __float_as_int(c.z), E2 = __float_as_int(c.w);
        float4 o;
        float* of = (float*)&o;
#pragma unroll
        for (int ii = 0; ii < 4; ++ii) {
            const int e = 4 * q + ii;
            of[ii] = (e == E1) ? c.x : (e == E2) ? c.y : 0.f;
        }
        *(float4*)(out + (size_t)(tok0 + tt) * NEXP + q * 4) = o;
    }
}

extern "C" void kernel_launch(void* const* d_in, const int* in_sizes, int n_in,
                              void* d_out, int out_size, void* d_ws, size_t ws_size,
                              hipStream_t stream)
{
    const float* x   = (const float*)d_in[0];
    const float* emb = (const float*)d_in[1];
    float* out = (float*)d_out;
    uint4* wsb = (uint4*)d_ws;                   // 384 KiB chunk-contiguous frags

    prepack_kernel<<<32, 256, 0, stream>>>(emb, wsb);

    const int n_tokens = in_sizes[0] / HDIM;     // 32768
    const int nblocks  = n_tokens / TPB;         // 1024

    router_kernel<<<nblocks, NTHREADS, 0, stream>>>(x, wsb, out);
}

// Round 19
// 44.678 us; speedup vs baseline: 1.3816x; 1.3816x over previous
//
#include <hip/hip_runtime.h>
#include <math.h>
#include <stdint.h>

// Router: scores = x @ emb^T [32768 x 64] fp32-accurate, top-2 + 2-way softmax.
//
// Error-free split-bf16 MFMA (rounds 9-18): 3 bf16 limbs per fp32 operand,
// 6 limb-product MFMA passes accumulated in fp32 (~3e-7 error).
// Round-19 structural fix: wave = 16 tokens x ALL 64 experts (round 9's shape)
// on the staged-LDS machinery (rounds 15-18). Kills the 4x redundant split8
// (VALU busy ~30 -> ~12 us) and improves LDS-read/MFMA ratio (25 -> ~18 us):
// per wave-chunk: 4 A-reads + 2 split8 + 24 B-reads feed 48 MFMAs (vs round
// 18's 10 reads + 2 splits per 12 MFMAs, duplicated 4x across waves).
// Block = 256 thr = 4 waves = 64 tokens; LDS 56 KB -> 2 blocks/CU, grid 512.
// Epilogue: wave-local top-2 (4 tiles in-register + 16-lane shfl merge),
// NO inter-wave merge. Counted vmcnt: X=4, B=6 loads/thread; steady
// outstanding 14 -> vmcnt(4) keeps next X in flight; vmcnt(0) only last iter.

typedef __attribute__((ext_vector_type(8))) short short8;
typedef __attribute__((ext_vector_type(4))) float f32x4;

constexpr int HDIM = 1024;
constexpr int NEXP = 64;
constexpr int TPB  = 64;            // tokens per block
constexpr int NTHREADS = 256;       // 4 waves
constexpr int NCHUNK = 16;          // 64-k chunks

__device__ __forceinline__ uint32_t cvtpk_bf16(float lo, float hi) {
    uint32_t r;
    asm("v_cvt_pk_bf16_f32 %0, %1, %2" : "=v"(r) : "v"(lo), "v"(hi));
    return r;
}

// RNE 3-limb bf16 split of 8 fp32 values; outputs packed frag words.
__device__ __forceinline__ void split8(const float4& A, const float4& B,
                                       uint32_t w0[4], uint32_t w1[4],
                                       uint32_t w2[4])
{
    const float p[8] = {A.x, A.y, A.z, A.w, B.x, B.y, B.z, B.w};
#pragma unroll
    for (int m = 0; m < 4; ++m) {
        const float lo = p[2 * m], hi = p[2 * m + 1];
        const uint32_t c0 = cvtpk_bf16(lo, hi);
        const float l0 = __uint_as_float(c0 << 16);
        const float h0 = __uint_as_float(c0 & 0xFFFF0000u);
        const float rl = lo - l0, rh = hi - h0;         // exact
        const uint32_t c1 = cvtpk_bf16(rl, rh);
        const float l1 = __uint_as_float(c1 << 16);
        const float h1 = __uint_as_float(c1 & 0xFFFF0000u);
        const uint32_t c2 = cvtpk_bf16(rl - l1, rh - h1);
        w0[m] = c0; w1[m] = c1; w2[m] = c2;
    }
}

__device__ __forceinline__ short8 frag_of(uint32_t a, uint32_t b,
                                          uint32_t c, uint32_t d) {
    union { uint4 u; short8 s; } cv;
    cv.u = make_uint4(a, b, c, d);
    return cv.s;
}
__device__ __forceinline__ short8 frag_of4(const uint4& v) {
    union { uint4 u; short8 s; } cv;
    cv.u = v;
    return cv.s;
}

// prepack, chunk-contiguous for linear staging (same layout as rounds 15-18):
// wsb[c*1536 + ((jkk*4 + t)*3 + limb)*64 + lane] =
//   limb of emb[t*16+(lane&15)][(c*2+jkk)*32 + (lane>>4)*8 .. +7] as bf16x8.
__global__ __launch_bounds__(256)
void prepack_kernel(const float* __restrict__ emb, uint4* __restrict__ wsb)
{
    const int f2   = blockIdx.x * 256 + threadIdx.x;   // 0..8191
    const int lane = f2 & 63;
    const int t    = (f2 >> 6) & 3;
    const int jkk  = (f2 >> 8) & 1;
    const int c    = f2 >> 9;
    const int e    = t * 16 + (lane & 15);
    const int k0   = (c * 2 + jkk) * 32 + (lane >> 4) * 8;
    const float4 A = *(const float4*)(emb + (size_t)e * HDIM + k0);
    const float4 B = *(const float4*)(emb + (size_t)e * HDIM + k0 + 4);
    uint32_t w0[4], w1[4], w2[4];
    split8(A, B, w0, w1, w2);
    const int ob = c * 1536 + ((jkk * 4 + t) * 3) * 64 + lane;
    wsb[ob]       = make_uint4(w0[0], w0[1], w0[2], w0[3]);
    wsb[ob + 64]  = make_uint4(w1[0], w1[1], w1[2], w1[3]);
    wsb[ob + 128] = make_uint4(w2[0], w2[1], w2[2], w2[3]);
}

__global__ __launch_bounds__(NTHREADS, 2)
void router_kernel(const float* __restrict__ x,
                   const uint4* __restrict__ wsb,
                   float* __restrict__ out)
{
    __shared__ float4 xs[2][TPB][16];   // 32 KiB, x[token][quad^(token&15)]
    __shared__ uint4  bs[1536];         // 24 KiB, staged B-frags (one chunk)

    const int tid  = threadIdx.x;
    const int lane = tid & 63;
    const int m    = tid >> 6;          // wave id: tokens [16m, 16m+16)
    const int tok0 = blockIdx.x * TPB;
    const int col  = lane & 15;         // token-in-tile (A) / expert col (C)
    const int grp  = lane >> 4;         // k-slice within kk

    // x stage: 4 loads/thread (64 rows x 16 quads = 1024); XOR swizzle folded
    // into the per-lane GLOBAL source; LDS dest linear in thread order.
#define STAGE_X(P, C)                                                          \
    do {                                                                       \
        _Pragma("unroll")                                                      \
        for (int jj = 0; jj < 4; ++jj) {                                       \
            const int g_ = jj * NTHREADS + tid;                                \
            const int r_ = g_ >> 4, q_ = g_ & 15;                              \
            const float* src = x + (size_t)(tok0 + r_) * HDIM + (C) * 64       \
                                 + ((q_ ^ (r_ & 15)) * 4);                     \
            __builtin_amdgcn_global_load_lds(                                  \
                (const __attribute__((address_space(1))) void*)src,            \
                (__attribute__((address_space(3))) void*)&xs[P][r_][q_],       \
                16, 0, 0);                                                     \
        }                                                                      \
    } while (0)

    // B stage: 6 loads/thread, chunk-contiguous wsb image -> bs (linear).
#define STAGE_B(C)                                                             \
    do {                                                                       \
        _Pragma("unroll")                                                      \
        for (int jj = 0; jj < 6; ++jj) {                                       \
            const int f_ = jj * NTHREADS + tid;                                \
            __builtin_amdgcn_global_load_lds(                                  \
                (const __attribute__((address_space(1))) void*)                \
                    (wsb + (C) * 1536 + f_),                                   \
                (__attribute__((address_space(3))) void*)&bs[f_],              \
                16, 0, 0);                                                     \
        }                                                                      \
    } while (0)

    // wave-local accumulators: acc[t] = tokens [16m,16m+16) x experts [16t,+16)
    f32x4 acc[4] = {{0,0,0,0}, {0,0,0,0}, {0,0,0,0}, {0,0,0,0}};

    STAGE_X(0, 0);
    STAGE_B(0);
    STAGE_X(1, 1);

#pragma unroll 1
    for (int c = 0; c < NCHUNK; ++c) {
        // Ledger: issue order ... B(c)[6], X(c+2)[4]; at top of iter c the
        // 14 possibly-outstanding are X(c)4+B(c)6+X(c+1)4 -> vmcnt(4) retires
        // exactly X(c)+B(c), keeps X(c+1) in flight. Last iter drains.
        if (c < NCHUNK - 1) {
            asm volatile("s_waitcnt vmcnt(4)" ::: "memory");
        } else {
            asm volatile("s_waitcnt vmcnt(0)" ::: "memory");
        }
        __builtin_amdgcn_s_barrier();
        asm volatile("" ::: "memory");

        const int p = c & 1;
        const int r = 16 * m + col;
#pragma unroll
        for (int jkk = 0; jkk < 2; ++jkk) {
            const int q0 = jkk * 8 + grp * 2;
            const float4 a0 = xs[p][r][(q0    ) ^ col];
            const float4 a1 = xs[p][r][(q0 + 1) ^ col];

            uint32_t wa0[4], wa1[4], wa2[4];
            split8(a0, a1, wa0, wa1, wa2);
            const short8 fA0 = frag_of(wa0[0], wa0[1], wa0[2], wa0[3]);
            const short8 fA1 = frag_of(wa1[0], wa1[1], wa1[2], wa1[3]);
            const short8 fA2 = frag_of(wa2[0], wa2[1], wa2[2], wa2[3]);

#pragma unroll
            for (int t = 0; t < 4; ++t) {
                const int bf = ((jkk * 4 + t) * 3) * 64 + lane;
                const short8 fb0 = frag_of4(bs[bf]);
                const short8 fb1 = frag_of4(bs[bf + 64]);
                const short8 fb2 = frag_of4(bs[bf + 128]);

                f32x4 a = acc[t];
                a = __builtin_amdgcn_mfma_f32_16x16x32_bf16(fA2, fb0, a, 0,0,0);
                a = __builtin_amdgcn_mfma_f32_16x16x32_bf16(fA0, fb2, a, 0,0,0);
                a = __builtin_amdgcn_mfma_f32_16x16x32_bf16(fA1, fb1, a, 0,0,0);
                a = __builtin_amdgcn_mfma_f32_16x16x32_bf16(fA1, fb0, a, 0,0,0);
                a = __builtin_amdgcn_mfma_f32_16x16x32_bf16(fA0, fb1, a, 0,0,0);
                a = __builtin_amdgcn_mfma_f32_16x16x32_bf16(fA0, fb0, a, 0,0,0);
                acc[t] = a;
            }
        }

        __builtin_amdgcn_s_barrier();   // all waves done reading bs / xs[p]
        asm volatile("" ::: "memory");
        if (c + 1 < NCHUNK) STAGE_B(c + 1);
        if (c + 2 < NCHUNK) STAGE_X(p, c + 2);   // xs[p] just fully consumed
    }
#undef STAGE_X
#undef STAGE_B

    // ---- epilogue: wave-local top-2 over all 64 experts ----
    // acc[t][i]: token 16m + grp*4 + i, expert 16t + col.
    __syncthreads();
    float4* cand2 = (float4*)&bs[0];    // [64 tokens] (p1,p2,E1,E2), aliased

#define INS(v, e)                                                              \
    do {                                                                       \
        const float _v = (v); const int _e = (e);                              \
        if (_v > V1 || (_v == V1 && _e < E1)) {                                \
            V2 = V1; E2 = E1; V1 = _v; E1 = _e;                                \
        } else if (_v > V2 || (_v == V2 && _e < E2)) {                         \
            V2 = _v; E2 = _e;                                                  \
        }                                                                      \
    } while (0)

#pragma unroll
    for (int i = 0; i < 4; ++i) {
        float V1 = acc[0][i]; int E1 = col;
        float V2 = -INFINITY; int E2 = NEXP;
        INS(acc[1][i], 16 + col);
        INS(acc[2][i], 32 + col);
        INS(acc[3][i], 48 + col);
#pragma unroll
        for (int mk = 1; mk <= 8; mk <<= 1) {
            const float pv1 = __shfl_xor(V1, mk, 64);
            const int   pe1 = __shfl_xor(E1, mk, 64);
            const float pv2 = __shfl_xor(V2, mk, 64);
            const int   pe2 = __shfl_xor(E2, mk, 64);
            INS(pv1, pe1);
            INS(pv2, pe2);
        }
        if (col == 0) {
            const float et = expf(V2 - V1);
            float4 c2;
            c2.x = 1.f / (1.f + et);
            c2.y = et / (1.f + et);
            c2.z = __int_as_float(E1);
            c2.w = __int_as_float(E2);
            cand2[16 * m + grp * 4 + i] = c2;
        }
    }
#undef INS
    __syncthreads();

    // ---- coalesced output: 64 tokens x 16 quads = 1024 float4 (4/thread) ----
#pragma unroll
    for (int jj = 0; jj < 4; ++jj) {
        const int G = jj * NTHREADS + tid;     // 0..1023
        const int tt = G >> 4, q = G & 15;
        const float4 c = cand2[tt];
        const int E1 = __float_as_int(c.z), E2 = __float_as_int(c.w);
        float4 o;
        float* of = (float*)&o;
#pragma unroll
        for (int ii = 0; ii < 4; ++ii) {
            const int e = 4 * q + ii;
            of[ii] = (e == E1) ? c.x : (e == E2) ? c.y : 0.f;
        }
        *(float4*)(out + (size_t)(tok0 + tt) * NEXP + q * 4) = o;
    }
}

extern "C" void kernel_launch(void* const* d_in, const int* in_sizes, int n_in,
                              void* d_out, int out_size, void* d_ws, size_t ws_size,
                              hipStream_t stream)
{
    const float* x   = (const float*)d_in[0];
    const float* emb = (const float*)d_in[1];
    float* out = (float*)d_out;
    uint4* wsb = (uint4*)d_ws;                   // 384 KiB chunk-contiguous frags

    prepack_kernel<<<32, 256, 0, stream>>>(emb, wsb);

    const int n_tokens = in_sizes[0] / HDIM;     // 32768
    const int nblocks  = n_tokens / TPB;         // 512

    router_kernel<<<nblocks, NTHREADS, 0, stream>>>(x, wsb, out);
}

// Round 20
// 44.245 us; speedup vs baseline: 1.3951x; 1.0098x over previous
//
#include <hip/hip_runtime.h>
#include <math.h>
#include <stdint.h>

// Router: scores = x @ emb^T [32768 x 64] fp32-accurate, top-2 + 2-way softmax.
//
// Error-free split-bf16 MFMA (rounds 9-19): 3 bf16 limbs per fp32 operand,
// 6 limb-product MFMA passes accumulated in fp32 (~3e-7 error).
// Round 19 (44.7us) proved redundancy-kill is the lever; but zero-redundancy
// at 16-tok/wave caps TLP at 2 waves/SIMD (128 tokens/CU / 16). This round
// doubles TLP with ZERO new redundancy via in-block K-SPLIT x2: 512 thr =
// 8 waves = 4 token-tiles x 2 K-halves; wave = 16 tok x 64 exp x 512 k.
// Chunk = 32 k, both halves stream concurrently: LDS = xs 32K + bs 24K =
// 57.3 KB -> 2 blocks/CU = 4 waves/SIMD. Same total LDS reads / splits /
// MFMAs per CU as round 19. Deterministic K-half merge via LDS partial sum.
// Existing prepack is already 32k-chunk-contiguous (ch*768) -- unchanged.

typedef __attribute__((ext_vector_type(8))) short short8;
typedef __attribute__((ext_vector_type(4))) float f32x4;

constexpr int HDIM = 1024;
constexpr int NEXP = 64;
constexpr int TPB  = 64;            // tokens per block
constexpr int NTHREADS = 512;       // 8 waves
constexpr int NITER = 16;           // 32-k steps per K-half

__device__ __forceinline__ uint32_t cvtpk_bf16(float lo, float hi) {
    uint32_t r;
    asm("v_cvt_pk_bf16_f32 %0, %1, %2" : "=v"(r) : "v"(lo), "v"(hi));
    return r;
}

// RNE 3-limb bf16 split of 8 fp32 values; outputs packed frag words.
__device__ __forceinline__ void split8(const float4& A, const float4& B,
                                       uint32_t w0[4], uint32_t w1[4],
                                       uint32_t w2[4])
{
    const float p[8] = {A.x, A.y, A.z, A.w, B.x, B.y, B.z, B.w};
#pragma unroll
    for (int m = 0; m < 4; ++m) {
        const float lo = p[2 * m], hi = p[2 * m + 1];
        const uint32_t c0 = cvtpk_bf16(lo, hi);
        const float l0 = __uint_as_float(c0 << 16);
        const float h0 = __uint_as_float(c0 & 0xFFFF0000u);
        const float rl = lo - l0, rh = hi - h0;         // exact
        const uint32_t c1 = cvtpk_bf16(rl, rh);
        const float l1 = __uint_as_float(c1 << 16);
        const float h1 = __uint_as_float(c1 & 0xFFFF0000u);
        const uint32_t c2 = cvtpk_bf16(rl - l1, rh - h1);
        w0[m] = c0; w1[m] = c1; w2[m] = c2;
    }
}

__device__ __forceinline__ short8 frag_of(uint32_t a, uint32_t b,
                                          uint32_t c, uint32_t d) {
    union { uint4 u; short8 s; } cv;
    cv.u = make_uint4(a, b, c, d);
    return cv.s;
}
__device__ __forceinline__ short8 frag_of4(const uint4& v) {
    union { uint4 u; short8 s; } cv;
    cv.u = v;
    return cv.s;
}

// prepack (identical layout to rounds 15-19; 32k-chunk ch = c*2+jkk is
// contiguous at wsb[ch*768 + (t*3+limb)*64 + lane]):
__global__ __launch_bounds__(256)
void prepack_kernel(const float* __restrict__ emb, uint4* __restrict__ wsb)
{
    const int f2   = blockIdx.x * 256 + threadIdx.x;   // 0..8191
    const int lane = f2 & 63;
    const int t    = (f2 >> 6) & 3;
    const int jkk  = (f2 >> 8) & 1;
    const int c    = f2 >> 9;
    const int e    = t * 16 + (lane & 15);
    const int k0   = (c * 2 + jkk) * 32 + (lane >> 4) * 8;
    const float4 A = *(const float4*)(emb + (size_t)e * HDIM + k0);
    const float4 B = *(const float4*)(emb + (size_t)e * HDIM + k0 + 4);
    uint32_t w0[4], w1[4], w2[4];
    split8(A, B, w0, w1, w2);
    const int ob = c * 1536 + ((jkk * 4 + t) * 3) * 64 + lane;
    wsb[ob]       = make_uint4(w0[0], w0[1], w0[2], w0[3]);
    wsb[ob + 64]  = make_uint4(w1[0], w1[1], w1[2], w1[3]);
    wsb[ob + 128] = make_uint4(w2[0], w2[1], w2[2], w2[3]);
}

__global__ __launch_bounds__(NTHREADS, 4)
void router_kernel(const float* __restrict__ x,
                   const uint4* __restrict__ wsb,
                   float* __restrict__ out)
{
    // 57344 B total -> 2 blocks/CU. Epilogue aliases into xs / bs.
    __shared__ float4 xs[2][2][TPB][8];  // 32 KiB, [buf][half][token][quad^]
    __shared__ uint4  bs[2][768];        // 24 KiB, [half][staged B chunk]

    const int tid  = threadIdx.x;
    const int lane = tid & 63;
    const int W    = tid >> 6;          // wave 0..7
    const int m    = W & 3;             // token tile: tokens [16m, 16m+16)
    const int h    = W >> 2;            // K-half: chunks [16h, 16h+16)
    const int tok0 = blockIdx.x * TPB;
    const int col  = lane & 15;
    const int grp  = lane >> 4;

    // x stage for BOTH halves' chunk C: 1024 float4, 2 loads/thread.
    // XOR swizzle (q^(r&7)) folded into global source; LDS dest linear.
#define STAGE_X(P, C)                                                          \
    do {                                                                       \
        _Pragma("unroll")                                                      \
        for (int jj = 0; jj < 2; ++jj) {                                       \
            const int g_  = jj * NTHREADS + tid;                               \
            const int hh_ = g_ >> 9, gg_ = g_ & 511;                           \
            const int r_ = gg_ >> 3, q_ = gg_ & 7;                             \
            const float* src = x + (size_t)(tok0 + r_) * HDIM                  \
                                 + (hh_ * 16 + (C)) * 32                       \
                                 + ((q_ ^ (r_ & 7)) * 4);                      \
            __builtin_amdgcn_global_load_lds(                                  \
                (const __attribute__((address_space(1))) void*)src,            \
                (__attribute__((address_space(3))) void*)&xs[P][hh_][r_][q_],  \
                16, 0, 0);                                                     \
        }                                                                      \
    } while (0)

    // B stage for BOTH halves' chunk C: 1536 uint4, 3 loads/thread.
#define STAGE_B(C)                                                             \
    do {                                                                       \
        _Pragma("unroll")                                                      \
        for (int jj = 0; jj < 3; ++jj) {                                       \
            const int f_  = jj * NTHREADS + tid;                               \
            const int hh_ = (f_ >= 768) ? 1 : 0;                               \
            const int of_ = f_ - hh_ * 768;                                    \
            __builtin_amdgcn_global_load_lds(                                  \
                (const __attribute__((address_space(1))) void*)                \
                    (wsb + (size_t)hh_ * 12288 + (C) * 768 + of_),             \
                (__attribute__((address_space(3))) void*)&bs[hh_][of_],        \
                16, 0, 0);                                                     \
        }                                                                      \
    } while (0)

    // wave-local accumulators: acc[t] = tokens [16m,+16) x experts [16t,+16),
    // partial over this wave's K-half.
    f32x4 acc[4] = {{0,0,0,0}, {0,0,0,0}, {0,0,0,0}, {0,0,0,0}};

    STAGE_X(0, 0);
    STAGE_B(0);
    STAGE_X(1, 1);

#pragma unroll 1
    for (int c = 0; c < NITER; ++c) {
        // Ledger: top of iter c outstanding = B(c)[3] + X(c+1)[2] ->
        // vmcnt(2) retires B(c) (and older), keeps X(c+1) in flight.
        if (c < NITER - 1) {
            asm volatile("s_waitcnt vmcnt(2)" ::: "memory");
        } else {
            asm volatile("s_waitcnt vmcnt(0)" ::: "memory");
        }
        __builtin_amdgcn_s_barrier();
        asm volatile("" ::: "memory");

        const int p  = c & 1;
        const int r  = 16 * m + col;
        const int rk = col & 7;
        const float4 a0 = xs[p][h][r][(2 * grp)     ^ rk];
        const float4 a1 = xs[p][h][r][(2 * grp + 1) ^ rk];

        uint32_t wa0[4], wa1[4], wa2[4];
        split8(a0, a1, wa0, wa1, wa2);
        const short8 fA0 = frag_of(wa0[0], wa0[1], wa0[2], wa0[3]);
        const short8 fA1 = frag_of(wa1[0], wa1[1], wa1[2], wa1[3]);
        const short8 fA2 = frag_of(wa2[0], wa2[1], wa2[2], wa2[3]);

#pragma unroll
        for (int t = 0; t < 4; ++t) {
            const int bf = (t * 3) * 64 + lane;
            const short8 fb0 = frag_of4(bs[h][bf]);
            const short8 fb1 = frag_of4(bs[h][bf + 64]);
            const short8 fb2 = frag_of4(bs[h][bf + 128]);

            f32x4 a = acc[t];
            a = __builtin_amdgcn_mfma_f32_16x16x32_bf16(fA2, fb0, a, 0,0,0);
            a = __builtin_amdgcn_mfma_f32_16x16x32_bf16(fA0, fb2, a, 0,0,0);
            a = __builtin_amdgcn_mfma_f32_16x16x32_bf16(fA1, fb1, a, 0,0,0);
            a = __builtin_amdgcn_mfma_f32_16x16x32_bf16(fA1, fb0, a, 0,0,0);
            a = __builtin_amdgcn_mfma_f32_16x16x32_bf16(fA0, fb1, a, 0,0,0);
            a = __builtin_amdgcn_mfma_f32_16x16x32_bf16(fA0, fb0, a, 0,0,0);
            acc[t] = a;
        }

        __builtin_amdgcn_s_barrier();   // all waves done reading bs / xs[p]
        asm volatile("" ::: "memory");
        if (c + 1 < NITER) STAGE_B(c + 1);
        if (c + 2 < NITER) STAGE_X(p, c + 2);   // xs[p] just fully consumed
    }
#undef STAGE_X
#undef STAGE_B

    // ---- K-half merge (deterministic: h=1 writes, h=0 adds once) ----
    __syncthreads();
    f32x4*  part  = (f32x4*)&xs[0][0][0][0];   // [m][t][lane], 16 KiB
    float4* cand2 = (float4*)&bs[0][0];        // [64 tokens] (p1,p2,E1,E2)

    if (h == 1) {
#pragma unroll
        for (int t = 0; t < 4; ++t) part[(m * 4 + t) * 64 + lane] = acc[t];
    }
    __syncthreads();

    if (h == 0) {
        f32x4 fin[4];
#pragma unroll
        for (int t = 0; t < 4; ++t)
            fin[t] = acc[t] + part[(m * 4 + t) * 64 + lane];

        // top-2 over all 64 experts; fin[t][i]: token 16m+grp*4+i,
        // expert 16t+col. 16-lane shfl merge, lowest index wins ties.
#define INS(v, e)                                                              \
        do {                                                                   \
            const float _v = (v); const int _e = (e);                          \
            if (_v > V1 || (_v == V1 && _e < E1)) {                            \
                V2 = V1; E2 = E1; V1 = _v; E1 = _e;                            \
            } else if (_v > V2 || (_v == V2 && _e < E2)) {                     \
                V2 = _v; E2 = _e;                                              \
            }                                                                  \
        } while (0)

#pragma unroll
        for (int i = 0; i < 4; ++i) {
            float V1 = fin[0][i]; int E1 = col;
            float V2 = -INFINITY; int E2 = NEXP;
            INS(fin[1][i], 16 + col);
            INS(fin[2][i], 32 + col);
            INS(fin[3][i], 48 + col);
#pragma unroll
            for (int mk = 1; mk <= 8; mk <<= 1) {
                const float pv1 = __shfl_xor(V1, mk, 64);
                const int   pe1 = __shfl_xor(E1, mk, 64);
                const float pv2 = __shfl_xor(V2, mk, 64);
                const int   pe2 = __shfl_xor(E2, mk, 64);
                INS(pv1, pe1);
                INS(pv2, pe2);
            }
            if (col == 0) {
                const float et = expf(V2 - V1);
                float4 c2;
                c2.x = 1.f / (1.f + et);
                c2.y = et / (1.f + et);
                c2.z = __int_as_float(E1);
                c2.w = __int_as_float(E2);
                cand2[16 * m + grp * 4 + i] = c2;
            }
        }
#undef INS
    }
    __syncthreads();

    // ---- coalesced output: 64 tokens x 16 quads = 1024 float4 (2/thread) ----
#pragma unroll
    for (int jj = 0; jj < 2; ++jj) {
        const int G = jj * NTHREADS + tid;     // 0..1023
        const int tt = G >> 4, q = G & 15;
        const float4 c = cand2[tt];
        const int E1 = __float_as_int(c.z), E2 = __float_as_int(c.w);
        float4 o;
        float* of = (float*)&o;
#pragma unroll
        for (int ii = 0; ii < 4; ++ii) {
            const int e = 4 * q + ii;
            of[ii] = (e == E1) ? c.x : (e == E2) ? c.y : 0.f;
        }
        *(float4*)(out + (size_t)(tok0 + tt) * NEXP + q * 4) = o;
    }
}

extern "C" void kernel_launch(void* const* d_in, const int* in_sizes, int n_in,
                              void* d_out, int out_size, void* d_ws, size_t ws_size,
                              hipStream_t stream)
{
    const float* x   = (const float*)d_in[0];
    const float* emb = (const float*)d_in[1];
    float* out = (float*)d_out;
    uint4* wsb = (uint4*)d_ws;                   // 384 KiB chunk-contiguous frags

    prepack_kernel<<<32, 256, 0, stream>>>(emb, wsb);

    const int n_tokens = in_sizes[0] / HDIM;     // 32768
    const int nblocks  = n_tokens / TPB;         // 512

    router_kernel<<<nblocks, NTHREADS, 0, stream>>>(x, wsb, out);
}